// Round 7
// baseline (199.941 us; speedup 1.0000x reference)
//
#include <hip/hip_runtime.h>

// LIF recurrence: u_t = decay*u_{t-1} + x_t - o_{t-1}*VTH ; o_t = (u_t - VTH > 0)
// x: [B=64, N=4096, T=100] f32, T contiguous (400 B per neuron row).
//
// R7: LDS-free, max-occupancy. R1..R6 post-mortem: every LDS-staged structure
// pins at ~2.2-2.5 TB/s visible HBM; common limiter hypothesis = too few
// waves/SIMD (LDS capped blocks/CU; 1-1.5 waves/SIMD = no latency hiding).
// Here: one thread per neuron, direct per-thread float4 reads (L1-amplified
// but L3-absorbed at HBM level -- R1 evidence: 75 MB visible reads), spikes
// bit-packed into 4 u32 VGPRs during compute (100 bits), then a wave-level
// store phase: lane gathers the owning lane's bit-word via __shfl, expands
// 4 bits -> float4, stores line-perfect 1 KB/wave-instr (fixes R1's 1.41x
// write amplification with zero LDS). 256-thread blocks, no barriers,
// no LDS -> all 4096 waves resident (16/CU = 4/SIMD).
//
// Exactness: decay=0.5 and o*VTH in {0,0.5} are exact products; FMA
// contraction cannot perturb u; spike output bit-matched numpy in R1-R6.

#define VTH 0.5f
#define T_STEPS 100
#define K 25   // float4s per neuron row

typedef float vfloat4 __attribute__((ext_vector_type(4)));

__global__ __launch_bounds__(256) void lif_kernel(const float* __restrict__ x,
                                                  const float* __restrict__ decay_p,
                                                  float* __restrict__ out) {
    const int tid = blockIdx.x * 256 + threadIdx.x;   // == neuron id
    const int lane = threadIdx.x & 63;
    const float decay = decay_p[0];

    const vfloat4* __restrict__ xrow = (const vfloat4*)(x + (size_t)tid * T_STEPS);

    // ---- Compute: serial over T in registers; spikes packed into b0..b3.
    unsigned b0 = 0, b1 = 0, b2 = 0, b3 = 0;
    float u = 0.0f, o = 0.0f;

#define STEP(val, t)                                                      \
    do {                                                                  \
        u = decay * u + (val) - o * VTH;                                  \
        o = (u > VTH) ? 1.0f : 0.0f;                                      \
        unsigned sb = (u > VTH) ? (1u << ((t) & 31)) : 0u;                \
        if ((t) < 32)      b0 |= sb;                                      \
        else if ((t) < 64) b1 |= sb;                                      \
        else if ((t) < 96) b2 |= sb;                                      \
        else               b3 |= sb;                                      \
    } while (0)

    #pragma unroll
    for (int i = 0; i < K; ++i) {
        vfloat4 v = xrow[i];
        STEP(v.x, 4 * i + 0);
        STEP(v.y, 4 * i + 1);
        STEP(v.z, 4 * i + 2);
        STEP(v.w, 4 * i + 3);
    }
#undef STEP

    // ---- Store: wave-cooperative, line-perfect. Wave owns a contiguous slab
    // of 64 neurons x 25 f4 = 1600 f4. Store k writes f4s [k*64 .. k*64+64):
    // lane gathers owner-lane's packed bits via __shfl and expands 4 -> float4.
    const size_t wave_slab_f4 = ((size_t)(tid >> 6)) * (64 * K);
    vfloat4* __restrict__ o4 = (vfloat4*)out + wave_slab_f4;

    #pragma unroll
    for (int k = 0; k < K; ++k) {
        const int idx = k * 64 + lane;        // f4 index within slab [0,1600)
        const int n = idx / 25;               // owning lane (neuron within wave)
        const int r = idx - n * 25;           // f4 within that neuron's row
        const int bt = r * 4;                 // starting time bit (0..96)

        const unsigned w0 = (unsigned)__shfl((int)b0, n);
        const unsigned w1 = (unsigned)__shfl((int)b1, n);
        const unsigned w2 = (unsigned)__shfl((int)b2, n);
        const unsigned w3 = (unsigned)__shfl((int)b3, n);

        const int word = bt >> 5;             // nibble never straddles a word
        const int off = bt & 31;
        const unsigned sel = (word & 2) ? ((word & 1) ? w3 : w2)
                                        : ((word & 1) ? w1 : w0);
        const unsigned nib = (sel >> off) & 0xFu;

        vfloat4 ov;
        ov.x = (nib & 1u) ? 1.0f : 0.0f;
        ov.y = (nib & 2u) ? 1.0f : 0.0f;
        ov.z = (nib & 4u) ? 1.0f : 0.0f;
        ov.w = (nib & 8u) ? 1.0f : 0.0f;
        __builtin_nontemporal_store(ov, &o4[k * 64 + lane]);
    }
}

extern "C" void kernel_launch(void* const* d_in, const int* in_sizes, int n_in,
                              void* d_out, int out_size, void* d_ws, size_t ws_size,
                              hipStream_t stream) {
    const float* x = (const float*)d_in[0];
    const float* decay = (const float*)d_in[1];
    float* out = (float*)d_out;

    const int n_neurons = in_sizes[0] / T_STEPS;   // 262,144
    const int grid = n_neurons / 256;              // 1024 blocks x 256 threads

    lif_kernel<<<grid, 256, 0, stream>>>(x, decay, out);
}

// Round 8
// 187.057 us; speedup vs baseline: 1.0689x; 1.0689x over previous
//
#include <hip/hip_runtime.h>

// LIF recurrence: u_t = decay*u_{t-1} + x_t - o_{t-1}*VTH ; o_t = (u_t - VTH > 0)
// x: [B=64, N=4096, T=100] f32, T contiguous (400 B per neuron row).
//
// FINAL (revert to R6, the session best: 63.7 us kernel).
// Slab/transpose dataflow: single-wave blocks (64 threads, no __syncthreads),
// block owns 64 consecutive neurons = contiguous 25.6 KB slab. Stage via
// coalesced float4 loads -> VGPR -> ds_write_b128 (flat slab mirror), compute
// the recurrence in-place in LDS (x -> o overwrite, per-lane row), store back
// with line-perfect 1 KB wave-wide non-temporal stores. 25.6 KB LDS ->
// 6 blocks/CU.
//
// Session evidence (R1-R7): six structurally distinct kernels (direct loads,
// DMA+barrier, multi-wave, barrier-free DMA pipeline, VGPR staging, LDS-free
// bit-pack) all land 63-76 us; every targeted counter moved as predicted
// (write-amp 1.41->1.0, occupancy 5.6->33%) without moving duration. Floor is
// external: harness restore/poison writebacks (~210 MB dirty L3) drain
// through HBM inside the kernel window; effective demand ~360 MB / 6.3 TB/s
// ~= 58 us. This kernel = 91% of that bound with minimal visible traffic
// (WRITE 102.4 MB = exact, FETCH 51 MB < input size via L3).
//
// Exactness: decay=0.5 and o*VTH in {0,0.5} are exact products, so FMA
// contraction cannot perturb u; spike output bit-matches numpy reference
// (absmax 0.0 every passing round).

#define VTH 0.5f
#define T_STEPS 100
#define W 64                  // neurons per block == threads per block (1 wave)
#define K 25                  // float4s per neuron row (100 floats)

typedef float vfloat4 __attribute__((ext_vector_type(4)));

__global__ __launch_bounds__(64) void lif_kernel(const float* __restrict__ x,
                                                 const float* __restrict__ decay_p,
                                                 float* __restrict__ out,
                                                 int n_neurons) {
    __shared__ vfloat4 lds4[W * K];   // 25,600 B flat mirror of this block's slab

    const int lane = threadIdx.x;
    const float decay = decay_p[0];
    const size_t base_f4 = (size_t)blockIdx.x * (W * K);

    const vfloat4* __restrict__ g4 = (const vfloat4*)x + base_f4;
    vfloat4* __restrict__ o4 = (vfloat4*)out + base_f4;

    // ---- Stage: 25 coalesced 1 KB wave-wide loads, then ds_write_b128 into
    // the flat slab layout.
    vfloat4 v[K];
    #pragma unroll
    for (int k = 0; k < K; ++k) v[k] = g4[k * W + lane];
    #pragma unroll
    for (int k = 0; k < K; ++k) lds4[k * W + lane] = v[k];

    // ---- Compute: lane owns neuron `lane`; row = float4s [lane*K, lane*K+K).
    // In-place overwrite x -> o. Single wave: no barrier; lgkmcnt orders ds ops.
    float u = 0.0f, o = 0.0f;
    #pragma unroll
    for (int i = 0; i < K; ++i) {
        vfloat4 t = lds4[lane * K + i];
        u = decay * u + t.x - o * VTH; o = (u > VTH) ? 1.0f : 0.0f; t.x = o;
        u = decay * u + t.y - o * VTH; o = (u > VTH) ? 1.0f : 0.0f; t.y = o;
        u = decay * u + t.z - o * VTH; o = (u > VTH) ? 1.0f : 0.0f; t.z = o;
        u = decay * u + t.w - o * VTH; o = (u > VTH) ? 1.0f : 0.0f; t.w = o;
        lds4[lane * K + i] = t;
    }

    // ---- Store: lane-contiguous LDS reads (2-way max = free), line-perfect
    // 1 KB wave-wide non-temporal stores.
    #pragma unroll
    for (int k = 0; k < K; ++k) {
        __builtin_nontemporal_store(lds4[k * W + lane], &o4[k * W + lane]);
    }
}

extern "C" void kernel_launch(void* const* d_in, const int* in_sizes, int n_in,
                              void* d_out, int out_size, void* d_ws, size_t ws_size,
                              hipStream_t stream) {
    const float* x = (const float*)d_in[0];
    const float* decay = (const float*)d_in[1];
    float* out = (float*)d_out;

    const int n_neurons = in_sizes[0] / T_STEPS;   // 262,144
    const int grid = n_neurons / W;                // 4096 single-wave blocks

    lif_kernel<<<grid, W, 0, stream>>>(x, decay, out, n_neurons);
}